// Round 2
// baseline (27.060 us; speedup 1.0000x reference)
//
#include <hip/hip_runtime.h>

#define N_ATOMS 262144
#define N_MOL 8192
#define MAX_Z 100
#define D 1024
#define NBLK 256
#define NTHR 256
#define NDOT (MAX_Z + 3)   // 100 embed dots + 3 w_pos dots

// Sync flags live in module globals: the harness poisons d_out/d_ws to 0xAA
// before timing, but never touches module data. Loader inits these to 0; the
// end-of-kernel reset protocol restores 0 after every invocation, so the
// invariant "both counters are 0 at kernel entry" holds for the correctness
// call and for every graph replay.
__device__ int g_ready = 0;
__device__ int g_done  = 0;

__global__ __launch_bounds__(NTHR) void fused_energy_kernel(
    const int* __restrict__ z, const float* __restrict__ pos,
    const int* __restrict__ batch,
    const float* __restrict__ embed, const float* __restrict__ w_pos,
    const float* __restrict__ w, const float* __restrict__ b,
    float* __restrict__ out, float* __restrict__ ewpw)
{
    const int blk = blockIdx.x, tid = threadIdx.x;
    __shared__ float red[NTHR];
    __shared__ float ew_lds[NDOT];

    // ---------------- phase 1: 103 dots + out init ----------------
    if (blk < NDOT) {
        const float* row = (blk < MAX_Z) ? embed + (size_t)blk * D
                                         : w_pos + (size_t)(blk - MAX_Z) * D;
        float s = 0.f;
        for (int j = tid; j < D; j += NTHR) s += row[j] * w[j];
        red[tid] = s;
        __syncthreads();
        for (int off = NTHR / 2; off > 0; off >>= 1) {
            if (tid < off) red[tid] += red[tid + off];
            __syncthreads();
        }
        if (tid == 0)
            __hip_atomic_store(&ewpw[blk], red[0], __ATOMIC_RELAXED,
                               __HIP_MEMORY_SCOPE_AGENT);
    }
    {   // every block inits its 32-entry slice of out (before the barrier,
        // so no atomicAdd anywhere can precede the init)
        const float bv = b[0];
        const int base = blk * (N_MOL / NBLK);
        if (tid < N_MOL / NBLK) out[base + tid] = bv;
    }

    // ---------------- grid barrier (all 256 blocks co-resident) ----------
    __syncthreads();
    if (tid == 0) {
        __threadfence();  // flush ewpw + out-init to coherence point
        __hip_atomic_fetch_add(&g_ready, 1, __ATOMIC_RELEASE,
                               __HIP_MEMORY_SCOPE_AGENT);
        while (__hip_atomic_load(&g_ready, __ATOMIC_RELAXED,
                                 __HIP_MEMORY_SCOPE_AGENT) < NBLK)
            __builtin_amdgcn_s_sleep(2);
    }
    __syncthreads();

    // stage the 103 scalars into LDS via agent-scope atomic loads
    // (cross-XCD safe regardless of fence subtleties)
    if (tid < NDOT)
        ew_lds[tid] = __hip_atomic_load(&ewpw[tid], __ATOMIC_RELAXED,
                                        __HIP_MEMORY_SCOPE_AGENT);
    __syncthreads();

    // ---------------- phase 2: atoms ----------------
    const float pw0 = ew_lds[MAX_Z + 0];
    const float pw1 = ew_lds[MAX_Z + 1];
    const float pw2 = ew_lds[MAX_Z + 2];
    const int lane = tid & 63;
    const int wv   = tid >> 6;
    const int wbase = blk * (N_ATOMS / NBLK) + wv * 256;

    #pragma unroll
    for (int t = 0; t < 4; ++t) {
        const int i  = wbase + t * 64 + lane;
        const int id = batch[i];
        const int zi = z[i];
        const float p0 = pos[3 * (size_t)i + 0];
        const float p1 = pos[3 * (size_t)i + 1];
        const float p2 = pos[3 * (size_t)i + 2];
        float v = ew_lds[zi] + p0 * pw0 + p1 * pw1 + p2 * pw2;

        // batch sorted -> segmented inclusive scan across the 64-lane wave
        #pragma unroll
        for (int off = 1; off < 64; off <<= 1) {
            float vu = __shfl_up(v, off);
            int   iu = __shfl_up(id, off);
            if (lane >= off && iu == id) v += vu;
        }
        const int idn = __shfl_down(id, 1);
        if (lane == 63 || idn != id) atomicAdd(&out[id], v);
    }

    // ---------------- reset protocol (keeps flags 0 across replays) ------
    __syncthreads();
    if (tid == 0) {
        int old = __hip_atomic_fetch_add(&g_done, 1, __ATOMIC_ACQ_REL,
                                         __HIP_MEMORY_SCOPE_AGENT);
        if (old == NBLK - 1) {   // genuinely-last block: everyone passed spin
            __hip_atomic_store(&g_ready, 0, __ATOMIC_RELAXED,
                               __HIP_MEMORY_SCOPE_AGENT);
            __hip_atomic_store(&g_done, 0, __ATOMIC_RELAXED,
                               __HIP_MEMORY_SCOPE_AGENT);
        }
    }
}

extern "C" void kernel_launch(void* const* d_in, const int* in_sizes, int n_in,
                              void* d_out, int out_size, void* d_ws, size_t ws_size,
                              hipStream_t stream) {
    const int*   atomic_numbers = (const int*)d_in[0];
    const float* pos            = (const float*)d_in[1];
    const int*   batch          = (const int*)d_in[2];
    const float* embed          = (const float*)d_in[3];
    const float* w_pos          = (const float*)d_in[4];
    const float* w              = (const float*)d_in[5];
    const float* b              = (const float*)d_in[6];
    float*       out            = (float*)d_out;
    float*       ewpw           = (float*)d_ws;

    fused_energy_kernel<<<NBLK, NTHR, 0, stream>>>(
        atomic_numbers, pos, batch, embed, w_pos, w, b, out, ewpw);
}

// Round 3
// 14.586 us; speedup vs baseline: 1.8553x; 1.8553x over previous
//
#include <hip/hip_runtime.h>

#define N_ATOMS 262144
#define N_MOL   8192
#define MAX_Z   100
#define D       1024
#define NDOT    (MAX_Z + 3)     // 100 embed rows + 3 w_pos rows
#define NBLK    128
#define NTHR    512
#define MPB     (N_MOL / NBLK)  // 64 molecules owned per block
#define WAVES   (NTHR / 64)     // 8

__global__ __launch_bounds__(NTHR) void fused_energy_kernel(
    const int* __restrict__ z, const float* __restrict__ pos,
    const int* __restrict__ batch,
    const float* __restrict__ embed, const float* __restrict__ w_pos,
    const float* __restrict__ w, const float* __restrict__ b,
    float* __restrict__ out)
{
    const int blk  = blockIdx.x, tid = threadIdx.x;
    const int lane = tid & 63,   wv  = tid >> 6;
    __shared__ float tab[NDOT];   // ew[z] and pw[0..2]
    __shared__ float mol[MPB];    // per-molecule partial sums
    __shared__ int   bounds[2];   // [lower, upper) atom range for this block

    if (tid < MPB) mol[tid] = 0.f;

    const int mol_base = blk * MPB;

    // ---- parallel lower_bound (waves 0 and 1; 3 rounds of 64 probes) ----
    // batch is sorted; N_ATOMS = 64*64*64 exactly.
    if (wv < 2) {
        const int V = mol_base + wv * MPB;      // wv=0: range start, wv=1: end
        int lower;
        int v1 = batch[lane * 4096];
        int c1 = __popcll(__ballot(v1 < V));
        if (c1 == 0) {
            lower = 0;                           // batch[0] >= V
        } else {
            int base1 = (c1 - 1) * 4096;         // batch[base1] < V
            int idx2  = base1 + (lane + 1) * 64;
            int v2    = (idx2 < N_ATOMS) ? batch[idx2] : 0x7fffffff;
            int c2    = __popcll(__ballot(v2 < V));
            int base2 = base1 + c2 * 64;         // batch[base2] < V
            int idx3  = base2 + 1 + lane;
            int v3    = (idx3 < N_ATOMS) ? batch[idx3] : 0x7fffffff;
            int c3    = __popcll(__ballot(v3 < V));
            lower = base2 + 1 + c3;
        }
        if (lane == 0) bounds[wv] = lower;
    }

    // ---- redundant per-block table: 103 dot products, rows strided on waves
    // lane caches its 16 w-elements (4x float4, coalesced: 4*lane + 256*k)
    float4 wc[4];
    #pragma unroll
    for (int k = 0; k < 4; ++k)
        wc[k] = *(const float4*)&w[4 * lane + 256 * k];

    for (int r = wv; r < NDOT; r += WAVES) {
        const float* row = (r < MAX_Z) ? embed + (size_t)r * D
                                       : w_pos + (size_t)(r - MAX_Z) * D;
        float s = 0.f;
        #pragma unroll
        for (int k = 0; k < 4; ++k) {
            float4 rv = *(const float4*)&row[4 * lane + 256 * k];
            s += rv.x * wc[k].x + rv.y * wc[k].y + rv.z * wc[k].z + rv.w * wc[k].w;
        }
        #pragma unroll
        for (int off = 32; off > 0; off >>= 1)
            s += __shfl_xor(s, off);
        if (lane == 0) tab[r] = s;
    }
    __syncthreads();

    // ---- atom phase: only this block's owned range ----
    const int lower = bounds[0], upper = bounds[1];
    const float pw0 = tab[MAX_Z + 0];
    const float pw1 = tab[MAX_Z + 1];
    const float pw2 = tab[MAX_Z + 2];

    for (int base = lower; base < upper; base += NTHR) {
        const int  i     = base + tid;
        const bool valid = i < upper;
        const int  ii    = valid ? i : (upper - 1);

        const int   id = valid ? batch[ii] : 0x7fffffff;
        const int   zi = z[ii];
        const float p0 = pos[3 * (size_t)ii + 0];
        const float p1 = pos[3 * (size_t)ii + 1];
        const float p2 = pos[3 * (size_t)ii + 2];
        float v = valid ? (tab[zi] + p0 * pw0 + p1 * pw1 + p2 * pw2) : 0.f;

        // segmented inclusive scan across the 64-lane wave (batch sorted)
        #pragma unroll
        for (int off = 1; off < 64; off <<= 1) {
            float vu = __shfl_up(v, off);
            int   iu = __shfl_up(id, off);
            if (lane >= off && iu == id) v += vu;
        }
        const int idn = __shfl_down(id, 1);
        if (valid && (lane == 63 || idn != id))
            atomicAdd(&mol[id - mol_base], v);   // LDS atomic, ~2-3/wave-chunk
    }
    __syncthreads();

    // ---- write owned outputs: exactly once, no init needed ----
    if (tid < MPB) out[mol_base + tid] = b[0] + mol[tid];
}

extern "C" void kernel_launch(void* const* d_in, const int* in_sizes, int n_in,
                              void* d_out, int out_size, void* d_ws, size_t ws_size,
                              hipStream_t stream) {
    const int*   atomic_numbers = (const int*)d_in[0];
    const float* pos            = (const float*)d_in[1];
    const int*   batch          = (const int*)d_in[2];
    const float* embed          = (const float*)d_in[3];
    const float* w_pos          = (const float*)d_in[4];
    const float* w              = (const float*)d_in[5];
    const float* b              = (const float*)d_in[6];
    float*       out            = (float*)d_out;

    fused_energy_kernel<<<NBLK, NTHR, 0, stream>>>(
        atomic_numbers, pos, batch, embed, w_pos, w, b, out);
}